// Round 1
// baseline (41.181 us; speedup 1.0000x reference)
//
#include <hip/hip_runtime.h>

// P = dW/dF for W(F) = 8*tr(C) + 10*J^2 - 56*log(J) + 0.2*(I4^2 + I5^2) - 44
// C = F^T F, J = det F, G = diag(4, .5, .5), I4 = tr(C G), I5 = tr(cof(C) G)
//
// Analytic gradient:
//   P = 16 F + [20 J^2 - 56 + 0.8 I5^2] F^-T + 0.8 I4 * F G - 0.8 I5 * F^-T G cofC
// with F^-T = cof(F)/J, cofC = cof(C).

#define SAMPLES_PER_BLOCK 256
#define FLOATS_PER_BLOCK (SAMPLES_PER_BLOCK * 9)

__global__ __launch_bounds__(256) void pk1_grad_kernel(
    const float* __restrict__ Fin, float* __restrict__ Pout, int total_floats)
{
    __shared__ float lds[FLOATS_PER_BLOCK];
    const int t = threadIdx.x;
    const int base = blockIdx.x * FLOATS_PER_BLOCK;

    // ---- coalesced staging: global -> LDS (dword per lane, contiguous) ----
#pragma unroll
    for (int i = 0; i < 9; ++i) {
        int g = base + i * 256 + t;
        lds[i * 256 + t] = (g < total_floats) ? Fin[g] : 1.0f; // pad benign
    }
    __syncthreads();

    // ---- per-thread compute: one sample from LDS (stride 9 -> 2-way bank alias, free) ----
    float f[9];
#pragma unroll
    for (int k = 0; k < 9; ++k) f[k] = lds[t * 9 + k];

    // cof(F): F^-T = cof(F)/J
    float c00 = f[4]*f[8] - f[5]*f[7];
    float c01 = f[5]*f[6] - f[3]*f[8];
    float c02 = f[3]*f[7] - f[4]*f[6];
    float c10 = f[2]*f[7] - f[1]*f[8];
    float c11 = f[0]*f[8] - f[2]*f[6];
    float c12 = f[1]*f[6] - f[0]*f[7];
    float c20 = f[1]*f[5] - f[2]*f[4];
    float c21 = f[2]*f[3] - f[0]*f[5];
    float c22 = f[0]*f[4] - f[1]*f[3];
    float J   = f[0]*c00 + f[1]*c01 + f[2]*c02;
    float invJ = 1.0f / J;

    // C = F^T F (symmetric)
    float C00 = f[0]*f[0] + f[3]*f[3] + f[6]*f[6];
    float C11 = f[1]*f[1] + f[4]*f[4] + f[7]*f[7];
    float C22 = f[2]*f[2] + f[5]*f[5] + f[8]*f[8];
    float C01 = f[0]*f[1] + f[3]*f[4] + f[6]*f[7];
    float C02 = f[0]*f[2] + f[3]*f[5] + f[6]*f[8];
    float C12 = f[1]*f[2] + f[4]*f[5] + f[7]*f[8];

    float I4 = 4.0f*C00 + 0.5f*(C11 + C22);

    // cof(C) (symmetric)
    float K00 = C11*C22 - C12*C12;
    float K11 = C00*C22 - C02*C02;
    float K22 = C00*C11 - C01*C01;
    float K01 = C02*C12 - C01*C22;
    float K02 = C01*C12 - C02*C11;
    float K12 = C01*C02 - C00*C12;

    float I5 = 4.0f*K00 + 0.5f*(K11 + K22);

    float J2    = J * J;
    float alpha = (20.0f*J2 - 56.0f + 0.8f*I5*I5) * invJ;  // coeff on cof(F)
    float beta  = 0.8f * I4;                                // coeff on F G
    float gamma = -0.8f * I5 * invJ;                        // coeff on cof(F) G cofC

    float cf[3][3] = {{c00,c01,c02},{c10,c11,c12},{c20,c21,c22}};
    float K[3][3]  = {{K00,K01,K02},{K01,K11,K12},{K02,K12,K22}};
    const float g0 = 4.0f, g1 = 0.5f, g2 = 0.5f;
    const float gv[3] = {g0, g1, g2};

    float p[9];
#pragma unroll
    for (int i = 0; i < 3; ++i) {
        // row i of cof(F) scaled by G
        float a0 = cf[i][0] * g0;
        float a1 = cf[i][1] * g1;
        float a2 = cf[i][2] * g2;
#pragma unroll
        for (int j = 0; j < 3; ++j) {
            float M = a0 * K[0][j] + a1 * K[1][j] + a2 * K[2][j];
            p[3*i + j] = (16.0f + beta * gv[j]) * f[3*i + j]
                       + alpha * cf[i][j]
                       + gamma * M;
        }
    }

#pragma unroll
    for (int k = 0; k < 9; ++k) lds[t * 9 + k] = p[k];
    __syncthreads();

    // ---- coalesced store: LDS -> global ----
#pragma unroll
    for (int i = 0; i < 9; ++i) {
        int g = base + i * 256 + t;
        if (g < total_floats) Pout[g] = lds[i * 256 + t];
    }
}

extern "C" void kernel_launch(void* const* d_in, const int* in_sizes, int n_in,
                              void* d_out, int out_size, void* d_ws, size_t ws_size,
                              hipStream_t stream) {
    const float* F = (const float*)d_in[0];
    float* P = (float*)d_out;
    int total_floats = in_sizes[0];           // N * 9 = 27,000,000
    int blocks = (total_floats + FLOATS_PER_BLOCK - 1) / FLOATS_PER_BLOCK;
    pk1_grad_kernel<<<blocks, 256, 0, stream>>>(F, P, total_floats);
}